// Round 9
// baseline (3757.847 us; speedup 1.0000x reference)
//
#include <hip/hip_runtime.h>

#define DK 1024
#define NB 32768
#define BM 128
#define BN 128
#define BKT 16

// Reference model (established by probe rounds 4-8): np reference = f32 numpy
// calling BLAS sgemm with KC=512 K-panels (AOCL/BLIS on EPYC host). Per output
// element: ascending-k single-accumulator f32 FMA chain per 512-panel; C
// updated in order after each panel: tot = (P0 + P1).
// Flush chain after k=512 => k-tile kt==31.
#define MASK_MAIN 0x0000000080000000ull

// MODE 0: y = x @ Pi^T (NT) -> idx (float) to out
// MODE 1: xhat = cent[idx] @ Pi (NN) -> resid = x - f32(xhat) to out
// MODE 2: p = resid @ S^T (NT) -> sign(p) to out
template<int MODE>
__global__ __launch_bounds__(256)
void gk(const float* __restrict__ A,
        const float* __restrict__ W,
        const float* __restrict__ X,
        const float* __restrict__ cent,
        const float* __restrict__ bnd,
        float* __restrict__ out)
{
    __shared__ float As[BKT][BM];
    __shared__ float Bs[BKT][BN];
    __shared__ float centS[8];

    const int tid = threadIdx.x;
    const int tx8 = tid & 15, ty8 = tid >> 4;
    const int m0 = blockIdx.y * BM;
    const int n0 = blockIdx.x * BN;

    const int arow = tid >> 1;
    const int ak0  = (tid & 1) * 8;
    const int brow = tid >> 4;
    const int bn0  = (tid & 15) * 8;

    if (MODE == 1 && tid < 8) centS[tid] = cent[tid];

    float chn[8][8], tot[8][8];
#pragma unroll
    for (int i = 0; i < 8; ++i)
#pragma unroll
        for (int j = 0; j < 8; ++j) { chn[i][j] = 0.0f; tot[i][j] = 0.0f; }

    for (int kt = 0; kt < DK / BKT; ++kt) {
        const int k0 = kt * BKT;
        __syncthreads();   // orders prev compute (and centS init) before staging

        // ---- A stage: As[k][m] ----
        {
            const float4 v0 = *(const float4*)&A[(size_t)(m0 + arow) * DK + k0 + ak0];
            const float4 v1 = *(const float4*)&A[(size_t)(m0 + arow) * DK + k0 + ak0 + 4];
            if (MODE == 1) {
                As[ak0 + 0][arow] = centS[(int)v0.x];
                As[ak0 + 1][arow] = centS[(int)v0.y];
                As[ak0 + 2][arow] = centS[(int)v0.z];
                As[ak0 + 3][arow] = centS[(int)v0.w];
                As[ak0 + 4][arow] = centS[(int)v1.x];
                As[ak0 + 5][arow] = centS[(int)v1.y];
                As[ak0 + 6][arow] = centS[(int)v1.z];
                As[ak0 + 7][arow] = centS[(int)v1.w];
            } else {
                As[ak0 + 0][arow] = v0.x;
                As[ak0 + 1][arow] = v0.y;
                As[ak0 + 2][arow] = v0.z;
                As[ak0 + 3][arow] = v0.w;
                As[ak0 + 4][arow] = v1.x;
                As[ak0 + 5][arow] = v1.y;
                As[ak0 + 6][arow] = v1.z;
                As[ak0 + 7][arow] = v1.w;
            }
        }

        // ---- B stage: Bs[k][n] ----
        if (MODE == 1) {
            // NN: Bs[k][n] = W[(k0+k)*DK + n0+n]
            const float4 w0 = *(const float4*)&W[(size_t)(k0 + brow) * DK + n0 + bn0];
            const float4 w1 = *(const float4*)&W[(size_t)(k0 + brow) * DK + n0 + bn0 + 4];
            *(float4*)&Bs[brow][bn0]     = w0;
            *(float4*)&Bs[brow][bn0 + 4] = w1;
        } else {
            // NT: Bs[k][n] = W[(n0+n)*DK + k0+k]
            const float4 w0 = *(const float4*)&W[(size_t)(n0 + arow) * DK + k0 + ak0];
            const float4 w1 = *(const float4*)&W[(size_t)(n0 + arow) * DK + k0 + ak0 + 4];
            Bs[ak0 + 0][arow] = w0.x;
            Bs[ak0 + 1][arow] = w0.y;
            Bs[ak0 + 2][arow] = w0.z;
            Bs[ak0 + 3][arow] = w0.w;
            Bs[ak0 + 4][arow] = w1.x;
            Bs[ak0 + 5][arow] = w1.y;
            Bs[ak0 + 6][arow] = w1.z;
            Bs[ak0 + 7][arow] = w1.w;
        }
        __syncthreads();

        // ---- ascending-k FMA chains ----
#pragma unroll
        for (int kk = 0; kk < BKT; ++kk) {
            float a[8], b[8];
            *(float4*)&a[0] = *(const float4*)&As[kk][ty8 * 8];
            *(float4*)&a[4] = *(const float4*)&As[kk][ty8 * 8 + 4];
            *(float4*)&b[0] = *(const float4*)&Bs[kk][tx8 * 8];
            *(float4*)&b[4] = *(const float4*)&Bs[kk][tx8 * 8 + 4];
#pragma unroll
            for (int i = 0; i < 8; ++i)
#pragma unroll
                for (int j = 0; j < 8; ++j)
                    chn[i][j] = fmaf(a[i], b[j], chn[i][j]);
        }

        // ---- KC=512 panel flush ----
        if ((MASK_MAIN >> kt) & 1ull) {
#pragma unroll
            for (int i = 0; i < 8; ++i)
#pragma unroll
                for (int j = 0; j < 8; ++j) { tot[i][j] += chn[i][j]; chn[i][j] = 0.0f; }
        }
    }
#pragma unroll
    for (int i = 0; i < 8; ++i)
#pragma unroll
        for (int j = 0; j < 8; ++j) tot[i][j] += chn[i][j];

    // ---- epilogue ----
    if constexpr (MODE == 0) {
        float bb[7];
#pragma unroll
        for (int t = 0; t < 7; ++t) bb[t] = bnd[t];
#pragma unroll
        for (int i = 0; i < 8; ++i)
#pragma unroll
            for (int j = 0; j < 8; ++j) {
                const int row = m0 + ty8 * 8 + i;
                const int col = n0 + tx8 * 8 + j;
                const float yf = tot[i][j];
                int id = 0;
#pragma unroll
                for (int t = 0; t < 7; ++t) id += (yf > bb[t]) ? 1 : 0;
                out[(size_t)row * DK + col] = (float)id;
            }
    } else if constexpr (MODE == 1) {
#pragma unroll
        for (int i = 0; i < 8; ++i)
#pragma unroll
            for (int j = 0; j < 8; ++j) {
                const int row = m0 + ty8 * 8 + i;
                const int col = n0 + tx8 * 8 + j;
                out[(size_t)row * DK + col] = X[(size_t)row * DK + col] - tot[i][j];
            }
    } else {
#pragma unroll
        for (int i = 0; i < 8; ++i)
#pragma unroll
            for (int j = 0; j < 8; ++j) {
                const int row = m0 + ty8 * 8 + i;
                const int col = n0 + tx8 * 8 + j;
                out[(size_t)row * DK + col] = (tot[i][j] >= 0.0f) ? 1.0f : -1.0f;
            }
    }
}

__global__ __launch_bounds__(256)
void norm_k(const float* __restrict__ resid, float* __restrict__ outn)
{
    const int lane = threadIdx.x & 63;
    const int row  = blockIdx.x * 4 + (threadIdx.x >> 6);
    const float* r = &resid[(size_t)row * DK];
    double s = 0.0;
    for (int i = lane; i < DK; i += 64) {
        const double v = (double)r[i];
        s += v * v;
    }
#pragma unroll
    for (int off = 32; off > 0; off >>= 1)
        s += __shfl_xor(s, off, 64);
    if (lane == 0) outn[row] = (float)sqrt(s);
}

// Fallback (small ws): residual parked in out_sign; each block owns a 16-row
// band, preloads it to LDS (race-free in-place), emits norms + signs.
__global__ __launch_bounds__(256)
void stage2_band(const float* __restrict__ RS,
                 const float* __restrict__ Sm,
                 float* __restrict__ out_sign,
                 float* __restrict__ out_norm)
{
    __shared__ float Rs[16][DK + 1];
    __shared__ float Bsh[BKT][64];

    const int tid = threadIdx.x;
    const int m0  = blockIdx.x * 16;

    for (int c = tid; c < 16 * 256; c += 256) {
        const int row = c >> 8, q = c & 255;
        const float4 v = *(const float4*)&RS[(size_t)(m0 + row) * DK + q * 4];
        Rs[row][q * 4 + 0] = v.x;
        Rs[row][q * 4 + 1] = v.y;
        Rs[row][q * 4 + 2] = v.z;
        Rs[row][q * 4 + 3] = v.w;
    }
    __syncthreads();

    {
        const int row = tid >> 4, sub = tid & 15;
        double s = 0.0;
        for (int c = sub; c < DK; c += 16) {
            const double v = (double)Rs[row][c];
            s += v * v;
        }
        s += __shfl_xor(s, 1, 16);
        s += __shfl_xor(s, 2, 16);
        s += __shfl_xor(s, 4, 16);
        s += __shfl_xor(s, 8, 16);
        if (sub == 0) out_norm[m0 + row] = (float)sqrt(s);
    }

    const int tx = tid & 15, ty = tid >> 4;
    const int srow = tid >> 2, s4 = tid & 3;

    for (int nt = 0; nt < 16; ++nt) {
        const int n0 = nt * 64;
        float chn[4] = {0.f, 0.f, 0.f, 0.f}, tot[4] = {0.f, 0.f, 0.f, 0.f};

        for (int kt = 0; kt < DK / BKT; ++kt) {
            const int k0 = kt * BKT;
            __syncthreads();
            const float4 w = *(const float4*)&Sm[(size_t)(n0 + srow) * DK + k0 + s4 * 4];
            Bsh[s4 * 4 + 0][srow] = w.x;
            Bsh[s4 * 4 + 1][srow] = w.y;
            Bsh[s4 * 4 + 2][srow] = w.z;
            Bsh[s4 * 4 + 3][srow] = w.w;
            __syncthreads();
#pragma unroll
            for (int kk = 0; kk < BKT; ++kk) {
                const float a = Rs[ty][k0 + kk];
#pragma unroll
                for (int j = 0; j < 4; ++j)
                    chn[j] = fmaf(a, Bsh[kk][tx * 4 + j], chn[j]);
            }
            if ((MASK_MAIN >> kt) & 1ull) {
#pragma unroll
                for (int j = 0; j < 4; ++j) { tot[j] += chn[j]; chn[j] = 0.0f; }
            }
        }
#pragma unroll
        for (int j = 0; j < 4; ++j) tot[j] += chn[j];
#pragma unroll
        for (int j = 0; j < 4; ++j)
            out_sign[(size_t)(m0 + ty) * DK + n0 + tx * 4 + j] =
                (tot[j] >= 0.0f) ? 1.0f : -1.0f;
    }
}

extern "C" void kernel_launch(void* const* d_in, const int* in_sizes, int n_in,
                              void* d_out, int out_size, void* d_ws, size_t ws_size,
                              hipStream_t stream)
{
    const float* x    = (const float*)d_in[0];
    const float* Pi   = (const float*)d_in[1];
    const float* S    = (const float*)d_in[2];
    const float* cent = (const float*)d_in[3];
    const float* bnd  = (const float*)d_in[4];

    float* out_idx  = (float*)d_out;
    float* out_sign = out_idx + (size_t)NB * DK;
    float* out_norm = out_idx + 2 * (size_t)NB * DK;

    const dim3 grid(DK / BN, NB / BM);      // (8, 256)
    const size_t needF32 = (size_t)NB * DK * sizeof(float);   // 134 MB

    gk<0><<<grid, 256, 0, stream>>>(x, Pi, (const float*)nullptr, cent, bnd, out_idx);

    if (ws_size >= needF32) {
        float* resid = (float*)d_ws;
        gk<1><<<grid, 256, 0, stream>>>(out_idx, Pi, x, cent, bnd, resid);
        gk<2><<<grid, 256, 0, stream>>>(resid, S, (const float*)nullptr, cent, bnd, out_sign);
        norm_k<<<NB / 4, 256, 0, stream>>>(resid, out_norm);
    } else {
        gk<1><<<grid, 256, 0, stream>>>(out_idx, Pi, x, cent, bnd, out_sign);
        stage2_band<<<NB / 16, 256, 0, stream>>>(out_sign, S, out_sign, out_norm);
    }
}

// Round 10
// 3463.473 us; speedup vs baseline: 1.0850x; 1.0850x over previous
//
#include <hip/hip_runtime.h>

#define DK 1024
#define NB 32768
#define BM 128
#define BN 128
#define BKT 32
#define NKT (DK / BKT)      // 32 k-tiles
#define FLUSH_KT 15         // flush chain after k=512 (KC=512 BLAS panel)
#define RSF 144             // LDS row stride in floats: 128 + 4-float gap per 32 cols

// gap-padded column index: +4 floats every 32 columns (breaks 32B-stride
// 4-way bank conflicts on fragment reads down to <=2-way, which is free)
__device__ __forceinline__ int gcol(int c) { return c + ((c >> 5) << 2); }

// Reference model (probe rounds 4-8, verified round 9): np ref = f32 sgemm,
// KC=512 K-panels; per element an ascending-k single-accumulator f32 FMA
// chain per panel, panel sums added in order. DO NOT reorder the fmaf chain.
// MODE 0: y = x @ Pi^T (NT) -> idx (float)
// MODE 1: xhat = cent[idx] @ Pi (NN) -> resid = x - xhat (f32)
// MODE 2: p = resid @ S^T (NT) -> sign(p)
template<int MODE>
__global__ __launch_bounds__(256)
void gk(const float* __restrict__ A,
        const float* __restrict__ W,
        const float* __restrict__ X,
        const float* __restrict__ cent,
        const float* __restrict__ bnd,
        float* __restrict__ out)
{
    __shared__ float As[BKT * RSF];
    __shared__ float Bs[BKT * RSF];
    __shared__ float centS[8];

    const int tid = threadIdx.x;
    const int tx8 = tid & 15, ty8 = tid >> 4;
    const int m0 = blockIdx.y * BM;
    const int n0 = blockIdx.x * BN;

    // A / NT-B staging geometry: thread -> (row arow, k-range [ak0, ak0+16))
    const int arow  = tid >> 1;
    const int ak0   = (tid & 1) * 16;
    const int arowG = arow + ((arow >> 5) << 2);
    // NN-B staging geometry (mode 1): thread -> (k-row brow, col range bn0+16)
    const int brow = tid >> 3;
    const int bn0  = (tid & 7) * 16;

    if (MODE == 1 && tid < 8) centS[tid] = cent[tid];

    const int aoff = ty8 * 8 + ((ty8 >> 2) << 2);
    const int boff = tx8 * 8 + ((tx8 >> 2) << 2);

    float4 pa[4], pb[4];   // in-flight prefetch registers

    auto load_tile = [&](int kt) {
        const int k0 = kt * BKT;
        const float* ap = &A[(size_t)(m0 + arow) * DK + k0 + ak0];
        pa[0] = *(const float4*)(ap + 0);
        pa[1] = *(const float4*)(ap + 4);
        pa[2] = *(const float4*)(ap + 8);
        pa[3] = *(const float4*)(ap + 12);
        if (MODE == 1) {
            const float* bp = &W[(size_t)(k0 + brow) * DK + n0 + bn0];
            pb[0] = *(const float4*)(bp + 0);
            pb[1] = *(const float4*)(bp + 4);
            pb[2] = *(const float4*)(bp + 8);
            pb[3] = *(const float4*)(bp + 12);
        } else {
            const float* bp = &W[(size_t)(n0 + arow) * DK + k0 + ak0];
            pb[0] = *(const float4*)(bp + 0);
            pb[1] = *(const float4*)(bp + 4);
            pb[2] = *(const float4*)(bp + 8);
            pb[3] = *(const float4*)(bp + 12);
        }
    };

    auto write_lds = [&]() {
        const float* pf = (const float*)pa;
        if (MODE == 1) {
#pragma unroll
            for (int e = 0; e < 16; ++e)
                As[(ak0 + e) * RSF + arowG] = centS[(int)pf[e]];
#pragma unroll
            for (int q = 0; q < 4; ++q)
                *(float4*)&Bs[brow * RSF + gcol(bn0 + q * 4)] = pb[q];
        } else {
#pragma unroll
            for (int e = 0; e < 16; ++e)
                As[(ak0 + e) * RSF + arowG] = pf[e];
            const float* qf = (const float*)pb;
#pragma unroll
            for (int e = 0; e < 16; ++e)
                Bs[(ak0 + e) * RSF + arowG] = qf[e];
        }
    };

    float chn[8][8], tot[8][8];
#pragma unroll
    for (int i = 0; i < 8; ++i)
#pragma unroll
        for (int j = 0; j < 8; ++j) { chn[i][j] = 0.0f; tot[i][j] = 0.0f; }

    // prologue: stage tile 0
    load_tile(0);
    __syncthreads();          // centS init visible (mode 1)
    write_lds();

    for (int kt = 0; kt < NKT; ++kt) {
        if (kt + 1 < NKT) load_tile(kt + 1);   // issue next tile's loads early
        __syncthreads();                       // current tile's LDS writes visible

#pragma unroll
        for (int kk = 0; kk < BKT; ++kk) {
            float a[8], b[8];
            *(float4*)&a[0] = *(const float4*)&As[kk * RSF + aoff];
            *(float4*)&a[4] = *(const float4*)&As[kk * RSF + aoff + 4];
            *(float4*)&b[0] = *(const float4*)&Bs[kk * RSF + boff];
            *(float4*)&b[4] = *(const float4*)&Bs[kk * RSF + boff + 4];
#pragma unroll
            for (int i = 0; i < 8; ++i)
#pragma unroll
                for (int j = 0; j < 8; ++j)
                    chn[i][j] = fmaf(a[i], b[j], chn[i][j]);
        }

        if (kt == FLUSH_KT) {  // KC=512 panel boundary
#pragma unroll
            for (int i = 0; i < 8; ++i)
#pragma unroll
                for (int j = 0; j < 8; ++j) { tot[i][j] += chn[i][j]; chn[i][j] = 0.0f; }
        }

        __syncthreads();                       // everyone done reading this tile
        if (kt + 1 < NKT) write_lds();         // park prefetched tile in LDS
    }
#pragma unroll
    for (int i = 0; i < 8; ++i)
#pragma unroll
        for (int j = 0; j < 8; ++j) tot[i][j] += chn[i][j];

    // ---- epilogue ----
    if constexpr (MODE == 0) {
        float bb[7];
#pragma unroll
        for (int t = 0; t < 7; ++t) bb[t] = bnd[t];
#pragma unroll
        for (int i = 0; i < 8; ++i) {
            const int row = m0 + ty8 * 8 + i;
#pragma unroll
            for (int jq = 0; jq < 2; ++jq) {
                float4 v;
#pragma unroll
                for (int e = 0; e < 4; ++e) {
                    const float yf = tot[i][jq * 4 + e];
                    int id = 0;
#pragma unroll
                    for (int t = 0; t < 7; ++t) id += (yf > bb[t]) ? 1 : 0;
                    ((float*)&v)[e] = (float)id;
                }
                *(float4*)&out[(size_t)row * DK + n0 + tx8 * 8 + jq * 4] = v;
            }
        }
    } else if constexpr (MODE == 1) {
#pragma unroll
        for (int i = 0; i < 8; ++i) {
            const int row = m0 + ty8 * 8 + i;
#pragma unroll
            for (int jq = 0; jq < 2; ++jq) {
                const int col = n0 + tx8 * 8 + jq * 4;
                const float4 xv = *(const float4*)&X[(size_t)row * DK + col];
                float4 v;
                v.x = xv.x - tot[i][jq * 4 + 0];
                v.y = xv.y - tot[i][jq * 4 + 1];
                v.z = xv.z - tot[i][jq * 4 + 2];
                v.w = xv.w - tot[i][jq * 4 + 3];
                *(float4*)&out[(size_t)row * DK + col] = v;
            }
        }
    } else {
#pragma unroll
        for (int i = 0; i < 8; ++i) {
            const int row = m0 + ty8 * 8 + i;
#pragma unroll
            for (int jq = 0; jq < 2; ++jq) {
                float4 v;
#pragma unroll
                for (int e = 0; e < 4; ++e)
                    ((float*)&v)[e] = (tot[i][jq * 4 + e] >= 0.0f) ? 1.0f : -1.0f;
                *(float4*)&out[(size_t)row * DK + n0 + tx8 * 8 + jq * 4] = v;
            }
        }
    }
}

__global__ __launch_bounds__(256)
void norm_k(const float* __restrict__ resid, float* __restrict__ outn)
{
    const int lane = threadIdx.x & 63;
    const int row  = blockIdx.x * 4 + (threadIdx.x >> 6);
    const float* r = &resid[(size_t)row * DK];
    double s = 0.0;
    for (int i = lane; i < DK; i += 64) {
        const double v = (double)r[i];
        s += v * v;
    }
#pragma unroll
    for (int off = 32; off > 0; off >>= 1)
        s += __shfl_xor(s, off, 64);
    if (lane == 0) outn[row] = (float)sqrt(s);
}

// Fallback (small ws): residual parked in out_sign; each block owns a 16-row
// band, preloads it to LDS (race-free in-place), emits norms + signs.
__global__ __launch_bounds__(256)
void stage2_band(const float* __restrict__ RS,
                 const float* __restrict__ Sm,
                 float* __restrict__ out_sign,
                 float* __restrict__ out_norm)
{
    __shared__ float Rs[16][DK + 1];
    __shared__ float Bsh[16][64];

    const int tid = threadIdx.x;
    const int m0  = blockIdx.x * 16;

    for (int c = tid; c < 16 * 256; c += 256) {
        const int row = c >> 8, q = c & 255;
        const float4 v = *(const float4*)&RS[(size_t)(m0 + row) * DK + q * 4];
        Rs[row][q * 4 + 0] = v.x;
        Rs[row][q * 4 + 1] = v.y;
        Rs[row][q * 4 + 2] = v.z;
        Rs[row][q * 4 + 3] = v.w;
    }
    __syncthreads();

    {
        const int row = tid >> 4, sub = tid & 15;
        double s = 0.0;
        for (int c = sub; c < DK; c += 16) {
            const double v = (double)Rs[row][c];
            s += v * v;
        }
        s += __shfl_xor(s, 1, 16);
        s += __shfl_xor(s, 2, 16);
        s += __shfl_xor(s, 4, 16);
        s += __shfl_xor(s, 8, 16);
        if (sub == 0) out_norm[m0 + row] = (float)sqrt(s);
    }

    const int tx = tid & 15, ty = tid >> 4;
    const int srow = tid >> 2, s4 = tid & 3;

    for (int nt = 0; nt < 16; ++nt) {
        const int n0 = nt * 64;
        float chn[4] = {0.f, 0.f, 0.f, 0.f}, tot[4] = {0.f, 0.f, 0.f, 0.f};

        for (int kt = 0; kt < 64; ++kt) {
            const int k0 = kt * 16;
            __syncthreads();
            const float4 w = *(const float4*)&Sm[(size_t)(n0 + srow) * DK + k0 + s4 * 4];
            Bsh[s4 * 4 + 0][srow] = w.x;
            Bsh[s4 * 4 + 1][srow] = w.y;
            Bsh[s4 * 4 + 2][srow] = w.z;
            Bsh[s4 * 4 + 3][srow] = w.w;
            __syncthreads();
#pragma unroll
            for (int kk = 0; kk < 16; ++kk) {
                const float a = Rs[ty][k0 + kk];
#pragma unroll
                for (int j = 0; j < 4; ++j)
                    chn[j] = fmaf(a, Bsh[kk][tx * 4 + j], chn[j]);
            }
            if (kt == 31) {   // k=512 panel boundary
#pragma unroll
                for (int j = 0; j < 4; ++j) { tot[j] += chn[j]; chn[j] = 0.0f; }
            }
        }
#pragma unroll
        for (int j = 0; j < 4; ++j) tot[j] += chn[j];
#pragma unroll
        for (int j = 0; j < 4; ++j)
            out_sign[(size_t)(m0 + ty) * DK + n0 + tx * 4 + j] =
                (tot[j] >= 0.0f) ? 1.0f : -1.0f;
    }
}

extern "C" void kernel_launch(void* const* d_in, const int* in_sizes, int n_in,
                              void* d_out, int out_size, void* d_ws, size_t ws_size,
                              hipStream_t stream)
{
    const float* x    = (const float*)d_in[0];
    const float* Pi   = (const float*)d_in[1];
    const float* S    = (const float*)d_in[2];
    const float* cent = (const float*)d_in[3];
    const float* bnd  = (const float*)d_in[4];

    float* out_idx  = (float*)d_out;
    float* out_sign = out_idx + (size_t)NB * DK;
    float* out_norm = out_idx + 2 * (size_t)NB * DK;

    const dim3 grid(DK / BN, NB / BM);      // (8, 256)
    const size_t needF32 = (size_t)NB * DK * sizeof(float);   // 134 MB

    gk<0><<<grid, 256, 0, stream>>>(x, Pi, (const float*)nullptr, cent, bnd, out_idx);

    if (ws_size >= needF32) {
        float* resid = (float*)d_ws;
        gk<1><<<grid, 256, 0, stream>>>(out_idx, Pi, x, cent, bnd, resid);
        gk<2><<<grid, 256, 0, stream>>>(resid, S, (const float*)nullptr, cent, bnd, out_sign);
        norm_k<<<NB / 4, 256, 0, stream>>>(resid, out_norm);
    } else {
        gk<1><<<grid, 256, 0, stream>>>(out_idx, Pi, x, cent, bnd, out_sign);
        stage2_band<<<NB / 16, 256, 0, stream>>>(out_sign, S, out_sign, out_norm);
    }
}